// Round 7
// baseline (90.375 us; speedup 1.0000x reference)
//
#include <hip/hip_runtime.h>
#include <math.h>

// B=16, N=2048, M=32, P=48, T=5, C=240
#define NN 2048
#define MM 32
#define PP 48
#define CC 240
#define PI_F 3.14159265358979323846f
#define LOG2E_F 1.4426950408889634f

// Pre-kernel: pack X [B,N,3] -> Xp [B,N] float4 (16B-aligned) in d_ws so the
// random neighbor gather is a single global_load_dwordx4 (1 line/lane instead
// of 3 separate dword instructions re-touching the same lines -> 3x fewer L1
// transactions on the scattered-gather hot path).
__global__ __launch_bounds__(256) void acp_prep(
    const float* __restrict__ X, float4* __restrict__ Xp)
{
    int i = blockIdx.x * 256 + threadIdx.x;      // 0..32767
    if (i < 16 * NN) {
        const float* s = X + 3 * (size_t)i;
        Xp[i] = make_float4(s[0], s[1], s[2], 0.0f);
    }
}

// One block per n: 512 threads = 8 waves; wave w owns pairs (b=w, b=w+8).
// Lane l -> filter p = l (lanes 48..63 duplicate p=l-48, discarded).
// Neighbors counting-sorted by type in LDS; neighbors with R > max(rc)
// dropped at insertion (they contribute exactly 0 for every filter).
// fc = 0.5*(cos(pi R/rc)+1) = cos^2(pi R/(2 rc)).
// exp via v_exp_f32 (log2e folded); cos via raw v_cos_f32 (revolutions:
// coeff = 0.25/rc, clamped at 0.25 rev = pi/2 -> fc=0 beyond cutoff).
// Segment bounds pushed to SGPRs via readfirstlane -> scalar loop control.
__global__ __launch_bounds__(512) void acp_fused(
    const float4* __restrict__ Xp,    // [B,N] packed coords
    const float* __restrict__ rc,     // [P]
    const float* __restrict__ rs,     // [P]
    const float* __restrict__ re,     // [P]
    const int*   __restrict__ Nbrs,   // [B,N,M]
    const int*   __restrict__ NbrsZ,  // [B,N,M]
    float* __restrict__ out)          // [B,N,240]
{
    __shared__ float sRs[16 * 33];    // type-sorted R per b, stride 33
    __shared__ int   sCnt[16 * 8];
    __shared__ int   sBase[16 * 8];
    __shared__ float sPrs[PP], sPre[PP], sPp2[PP];
    __shared__ float sRcMax;
    __shared__ float redS, redQ;

    const int tid  = threadIdx.x;
    const int n    = blockIdx.x;
    const int lane = tid & 63;
    const int wv   = tid >> 6;        // wave 0..7

    if (tid < PP) {
        sPrs[tid] = rs[tid];
        sPre[tid] = -re[tid] * LOG2E_F;        // exp(-re d^2)=exp2(sPre d^2)
        sPp2[tid] = 0.25f / rc[tid];           // revolutions coefficient
    }
    if (wv == 0) {                             // max rc via wave-0 butterfly
        float v = (lane < PP) ? rc[lane] : 0.0f;
        #pragma unroll
        for (int k = 1; k < 64; k <<= 1) v = fmaxf(v, __shfl_xor(v, k, 64));
        if (lane == 0) sRcMax = v;
    }
    if (tid == 0) { redS = 0.0f; redQ = 0.0f; }
    if (tid < 128) sCnt[tid] = 0;
    __syncthreads();

    // ---- Phase 1: gather + distance + counting-sort (all 512 threads) ----
    const float rcmax = sRcMax;
    float Rv = 0.0f;
    int   tv = -1, posv = 0, cv = tid >> 5;
    {
        int c  = cv;                  // b index 0..15
        int m  = tid & 31;
        int bn = c * NN + n;
        int nb = Nbrs[bn * MM + m];
        int z  = NbrsZ[bn * MM + m];
        int t = (z == 1) ? 0 : (z == 6) ? 1 : (z == 7) ? 2
              : (z == 8) ? 3 : (z == 16) ? 4 : -1;
        if (t >= 0) {
            float4 xo = Xp[bn];                // broadcast within 32-group
            float4 xn = Xp[c * NN + nb];       // single dwordx4 gather
            float dx = xn.x - xo.x;
            float dy = xn.y - xo.y;
            float dz = xn.z - xo.z;
            float R = sqrtf(dx * dx + dy * dy + dz * dz);
            if (R <= rcmax) {         // beyond every cutoff -> exact zero
                Rv = R;
                tv = t;
                posv = atomicAdd(&sCnt[c * 8 + t], 1);
            }
        }
    }
    __syncthreads();
    if (tid < 16) {
        int s = 0;
        #pragma unroll
        for (int t = 0; t < 5; ++t) { sBase[tid * 8 + t] = s; s += sCnt[tid * 8 + t]; }
    }
    __syncthreads();
    if (tv >= 0) sRs[cv * 33 + sBase[cv * 8 + tv] + posv] = Rv;
    __syncthreads();

    // ---- Phase 2: scalar-bound segmented loops, lane = filter p ----
    const int p = (lane < PP) ? lane : lane - PP;
    const float prs = sPrs[p];
    const float pre = sPre[p];
    const float pp2 = sPp2[p];

    float acc[2][5];
    #pragma unroll
    for (int g = 0; g < 2; ++g) {
        const int c = wv + g * 8;
        const float* Rrow = sRs + c * 33;
        #pragma unroll
        for (int t = 0; t < 5; ++t) {
            // wave-uniform bounds -> force into SGPRs: scalar loop control
            int s = __builtin_amdgcn_readfirstlane(sBase[c * 8 + t]);
            int e = s + __builtin_amdgcn_readfirstlane(sCnt[c * 8 + t]);
            float a = 0.0f;
            for (int m = s; m < e; ++m) {
                float R  = Rrow[m];            // broadcast LDS read
                float d  = R - prs;
                float w  = __builtin_amdgcn_exp2f(pre * d * d);
                float ct = __builtin_amdgcn_cosf(fminf(R * pp2, 0.25f));
                a = fmaf(w * ct, ct, a);       // w * cos^2
            }
            acc[g][t] = a;
        }
    }

    // ---- Epilogue: fused BatchNorm stats (per n over 16 b x 240 c) ----
    float s1 = 0.0f, s2 = 0.0f;
    if (lane < PP) {
        #pragma unroll
        for (int g = 0; g < 2; ++g)
            #pragma unroll
            for (int t = 0; t < 5; ++t) {
                float v = acc[g][t];
                s1 += v;
                s2 = fmaf(v, v, s2);
            }
    }
    #pragma unroll
    for (int k = 1; k < 64; k <<= 1) {
        s1 += __shfl_xor(s1, k, 64);
        s2 += __shfl_xor(s2, k, 64);
    }
    if (lane == 0) {
        atomicAdd(&redS, s1);
        atomicAdd(&redQ, s2);
    }
    __syncthreads();

    const float cnt_inv = 1.0f / 3840.0f;
    float mean = redS * cnt_inv;
    float var  = redQ * cnt_inv - mean * mean;
    float rstd = rsqrtf(var + 1e-5f);

    if (lane < PP) {
        #pragma unroll
        for (int g = 0; g < 2; ++g) {
            const int c = wv + g * 8;
            float* o = out + ((size_t)c * NN + n) * CC + p;
            #pragma unroll
            for (int t = 0; t < 5; ++t)
                o[t * PP] = (acc[g][t] - mean) * rstd;
        }
    }
}

extern "C" void kernel_launch(void* const* d_in, const int* in_sizes, int n_in,
                              void* d_out, int out_size, void* d_ws, size_t ws_size,
                              hipStream_t stream) {
    const float* X     = (const float*)d_in[0];
    const float* rc    = (const float*)d_in[1];
    const float* rs    = (const float*)d_in[2];
    const float* re    = (const float*)d_in[3];
    const int*   Nbrs  = (const int*)d_in[4];
    const int*   NbrsZ = (const int*)d_in[5];
    float* out = (float*)d_out;
    float4* Xp = (float4*)d_ws;          // 16*2048*16 B = 512 KB

    acp_prep<<<(16 * NN + 255) / 256, 256, 0, stream>>>(X, Xp);
    acp_fused<<<NN, 512, 0, stream>>>(Xp, rc, rs, re, Nbrs, NbrsZ, out);
}

// Round 8
// 87.663 us; speedup vs baseline: 1.0309x; 1.0309x over previous
//
#include <hip/hip_runtime.h>
#include <math.h>

// B=16, N=2048, M=32, P=48, T=5, C=240
#define NN 2048
#define MM 32
#define PP 48
#define CC 240
#define PI_F 3.14159265358979323846f
#define LOG2E_F 1.4426950408889634f

// One block per n: 256 threads = 4 waves; wave w owns b in {w, w+4, w+8, w+12}.
// (8 blocks/CU resident vs 4 for the 512-thread variant -> 2x more independent
// barrier domains to hide the HBM-latency Nbrs load + store drain behind.)
// Lane l -> filter p = l (lanes 48..63 duplicate p=l-48, discarded).
// Neighbors counting-sorted by type in LDS; neighbors with R > max(rc)
// dropped at insertion (they contribute exactly 0 for every filter).
// fc = 0.5*(cos(pi R/rc)+1) = cos^2(pi R/(2 rc)).
// exp via v_exp_f32 (log2e folded); cos via raw v_cos_f32 (revolutions:
// coeff = 0.25/rc, clamp at 0.25 rev = pi/2 -> fc=0 beyond cutoff).
// Segment bounds pushed to SGPRs via readfirstlane -> scalar loop control.
__global__ __launch_bounds__(256) void acp_fused(
    const float* __restrict__ X,      // [B,N,3]
    const float* __restrict__ rc,     // [P]
    const float* __restrict__ rs,     // [P]
    const float* __restrict__ re,     // [P]
    const int*   __restrict__ Nbrs,   // [B,N,M]
    const int*   __restrict__ NbrsZ,  // [B,N,M]
    float* __restrict__ out)          // [B,N,240]
{
    __shared__ float sRs[16 * 33];    // type-sorted R per b, stride 33
    __shared__ int   sCnt[16 * 8];
    __shared__ int   sBase[16 * 8];
    __shared__ float sPrs[PP], sPre[PP], sPp2[PP];
    __shared__ float sRcMax;
    __shared__ float redS, redQ;

    const int tid  = threadIdx.x;
    const int n    = blockIdx.x;
    const int lane = tid & 63;
    const int wv   = tid >> 6;        // wave 0..3

    if (tid < PP) {
        sPrs[tid] = rs[tid];
        sPre[tid] = -re[tid] * LOG2E_F;        // exp(-re d^2)=exp2(sPre d^2)
        sPp2[tid] = 0.25f / rc[tid];           // revolutions coefficient
    }
    if (wv == 0) {                             // max rc via wave-0 butterfly
        float v = (lane < PP) ? rc[lane] : 0.0f;
        #pragma unroll
        for (int k = 1; k < 64; k <<= 1) v = fmaxf(v, __shfl_xor(v, k, 64));
        if (lane == 0) sRcMax = v;
    }
    if (tid == 0) { redS = 0.0f; redQ = 0.0f; }
    if (tid < 128) sCnt[tid] = 0;
    __syncthreads();

    // ---- Phase 1: gather + distance + counting-sort (2 slots/thread) ----
    const float rcmax = sRcMax;
    float Rv[2];
    int   tv[2], posv[2], cv[2];
    #pragma unroll
    for (int k = 0; k < 2; ++k) {
        int slot = tid + k * 256;     // 0..511
        int c  = slot >> 5;           // b index 0..15
        int m  = slot & 31;
        cv[k] = c;
        tv[k] = -1;
        int bn = c * NN + n;
        int nb = Nbrs[bn * MM + m];
        int z  = NbrsZ[bn * MM + m];
        int t = (z == 1) ? 0 : (z == 6) ? 1 : (z == 7) ? 2
              : (z == 8) ? 3 : (z == 16) ? 4 : -1;
        if (t >= 0) {
            const float* xo = X + (size_t)bn * 3;
            const float* xn = X + (size_t)(c * NN + nb) * 3;
            float dx = xn[0] - xo[0];
            float dy = xn[1] - xo[1];
            float dz = xn[2] - xo[2];
            float R = sqrtf(dx * dx + dy * dy + dz * dz);
            if (R <= rcmax) {         // beyond every cutoff -> exact zero
                Rv[k] = R;
                tv[k] = t;
                posv[k] = atomicAdd(&sCnt[c * 8 + t], 1);
            }
        }
    }
    __syncthreads();
    if (tid < 16) {
        int s = 0;
        #pragma unroll
        for (int t = 0; t < 5; ++t) { sBase[tid * 8 + t] = s; s += sCnt[tid * 8 + t]; }
    }
    __syncthreads();
    #pragma unroll
    for (int k = 0; k < 2; ++k)
        if (tv[k] >= 0)
            sRs[cv[k] * 33 + sBase[cv[k] * 8 + tv[k]] + posv[k]] = Rv[k];
    __syncthreads();

    // ---- Phase 2: scalar-bound segmented loops, lane = filter p ----
    const int p = (lane < PP) ? lane : lane - PP;
    const float prs = sPrs[p];
    const float pre = sPre[p];
    const float pp2 = sPp2[p];

    float acc[4][5];
    #pragma unroll
    for (int g = 0; g < 4; ++g) {
        const int c = wv + g * 4;
        const float* Rrow = sRs + c * 33;
        #pragma unroll
        for (int t = 0; t < 5; ++t) {
            // wave-uniform bounds -> force into SGPRs: scalar loop control
            int s = __builtin_amdgcn_readfirstlane(sBase[c * 8 + t]);
            int e = s + __builtin_amdgcn_readfirstlane(sCnt[c * 8 + t]);
            float a = 0.0f;
            for (int m = s; m < e; ++m) {
                float R  = Rrow[m];            // broadcast LDS read
                float d  = R - prs;
                float w  = __builtin_amdgcn_exp2f(pre * d * d);
                float ct = __builtin_amdgcn_cosf(fminf(R * pp2, 0.25f));
                a = fmaf(w * ct, ct, a);       // w * cos^2
            }
            acc[g][t] = a;
        }
    }

    // ---- Epilogue: fused BatchNorm stats (per n over 16 b x 240 c) ----
    float s1 = 0.0f, s2 = 0.0f;
    if (lane < PP) {
        #pragma unroll
        for (int g = 0; g < 4; ++g)
            #pragma unroll
            for (int t = 0; t < 5; ++t) {
                float v = acc[g][t];
                s1 += v;
                s2 = fmaf(v, v, s2);
            }
    }
    #pragma unroll
    for (int k = 1; k < 64; k <<= 1) {
        s1 += __shfl_xor(s1, k, 64);
        s2 += __shfl_xor(s2, k, 64);
    }
    if (lane == 0) {
        atomicAdd(&redS, s1);
        atomicAdd(&redQ, s2);
    }
    __syncthreads();

    const float cnt_inv = 1.0f / 3840.0f;
    float mean = redS * cnt_inv;
    float var  = redQ * cnt_inv - mean * mean;
    float rstd = rsqrtf(var + 1e-5f);

    if (lane < PP) {
        #pragma unroll
        for (int g = 0; g < 4; ++g) {
            const int c = wv + g * 4;
            float* o = out + ((size_t)c * NN + n) * CC + p;
            #pragma unroll
            for (int t = 0; t < 5; ++t)
                o[t * PP] = (acc[g][t] - mean) * rstd;
        }
    }
}

extern "C" void kernel_launch(void* const* d_in, const int* in_sizes, int n_in,
                              void* d_out, int out_size, void* d_ws, size_t ws_size,
                              hipStream_t stream) {
    const float* X     = (const float*)d_in[0];
    const float* rc    = (const float*)d_in[1];
    const float* rs    = (const float*)d_in[2];
    const float* re    = (const float*)d_in[3];
    const int*   Nbrs  = (const int*)d_in[4];
    const int*   NbrsZ = (const int*)d_in[5];
    float* out = (float*)d_out;

    acp_fused<<<NN, 256, 0, stream>>>(X, rc, rs, re, Nbrs, NbrsZ, out);
}